// Round 4
// baseline (199.373 us; speedup 1.0000x reference)
//
#include <hip/hip_runtime.h>
#include <stdint.h>
#include <stddef.h>

// Problem constants (fixed by setup_inputs)
#define NB   2      // batch
#define NL   2048   // seq len
#define ND   512    // model dim
#define NH   8      // heads
#define DH   64     // dim head
#define LOG2E 1.44269504f
#define RG_TOT 32768  // NB*NH*NL rows of partials

typedef __attribute__((ext_vector_type(8))) short bf16x8;
typedef __attribute__((ext_vector_type(4))) float f32x4;

__device__ __forceinline__ unsigned short f2bf(float f) {
  union { float f; unsigned int u; } c; c.f = f;
  unsigned int u = c.u;
  unsigned int r = u + 0x7fffu + ((u >> 16) & 1u);
  return (unsigned short)(r >> 16);
}

__device__ __forceinline__ float fexp2(float x) {
#if __has_builtin(__builtin_amdgcn_exp2f)
  return __builtin_amdgcn_exp2f(x);
#else
  return exp2f(x);
#endif
}

// async global->LDS 16B copy; lanes of a wave must target base + lane*16
__device__ __forceinline__ void gl_lds16(const unsigned short* g, unsigned short* l) {
#if __has_builtin(__builtin_amdgcn_global_load_lds)
  __builtin_amdgcn_global_load_lds(
      (const __attribute__((address_space(1))) unsigned int*)g,
      (__attribute__((address_space(3))) unsigned int*)l, 16, 0, 0);
#else
  *(uint4*)l = *(const uint4*)g;
#endif
}

// ---------------------------------------------------------------------------
// f32 -> bf16 conversion for x, w_qkv, w_out + zero-padded positions buffer
// ---------------------------------------------------------------------------
#define XC  524288   // 4096*512/4
#define WQC 196608   // 1536*512/4
#define WOC 65536    // 512*512/4
#define TOTC (XC + WQC + WOC)
__global__ void cvt_f32_bf16(const float* __restrict__ x, const float* __restrict__ wq,
                             const float* __restrict__ wo, const float* __restrict__ positions,
                             const int* __restrict__ ns_p,
                             unsigned short* __restrict__ xb, unsigned short* __restrict__ wqb,
                             unsigned short* __restrict__ wob, float* __restrict__ pospad) {
  int idx = blockIdx.x * 256 + threadIdx.x;
  if (idx < TOTC) {
    const float* src; unsigned short* dst; int off;
    if (idx < XC)            { src = x;  dst = xb;  off = idx; }
    else if (idx < XC + WQC) { src = wq; dst = wqb; off = idx - XC; }
    else                     { src = wo; dst = wob; off = idx - XC - WQC; }
    float4 f = ((const float4*)src)[off];
    ushort4 o;
    o.x = f2bf(f.x); o.y = f2bf(f.y); o.z = f2bf(f.z); o.w = f2bf(f.w);
    ((ushort4*)dst)[off] = o;
  } else {
    int i2 = idx - TOTC;
    if (i2 < NB * 1024) {
      int b = i2 >> 10;
      int jj = (i2 & 1023) * 2;
      int Ls = ns_p[0];
      float4 o = make_float4(0.f, 0.f, 0.f, 0.f);
      if (jj < Ls) { o.x = positions[((size_t)b * Ls + jj) * 2];
                     o.y = positions[((size_t)b * Ls + jj) * 2 + 1]; }
      if (jj + 1 < Ls) { o.z = positions[((size_t)b * Ls + jj + 1) * 2];
                         o.w = positions[((size_t)b * Ls + jj + 1) * 2 + 1]; }
      *(float4*)&pospad[((size_t)b * NL + jj) * 2] = o;
    }
  }
}

// ---------------------------------------------------------------------------
// bf16 128x128-tile MFMA GEMM, SWAPPED orientation: A = weights (M=out-dim),
// B = tokens (N=4096). C row (quad/reg) = out-dim -> vectorized epilogues.
// MODE 0: A=w_qkv[1536x512] -> q(pre-scaled)/k/v bf16 [b,h,l,dh] (ushort4 st).
// MODE 1: A=w_out[512x512], B=attn -> f32 out[token][512] + bias (float4 st).
// ---------------------------------------------------------------------------
template<int MODE>
__global__ __launch_bounds__(256, 2) void gemm_bf16(
    const unsigned short* __restrict__ A, const unsigned short* __restrict__ Bm,
    const float* __restrict__ bias,
    unsigned short* __restrict__ qo, unsigned short* __restrict__ ko,
    unsigned short* __restrict__ vo, float* __restrict__ out, int K)
{
  __shared__ __align__(16) unsigned short As[128 * 32];
  __shared__ __align__(16) unsigned short Bs[128 * 32];
  const int tid = threadIdx.x, wid = tid >> 6, lane = tid & 63;
  const int quad = lane >> 4, l15 = lane & 15;
  const int m0 = blockIdx.x * 128, n0 = blockIdx.y * 128;
  const int wm = (wid >> 1) * 64, wn = (wid & 1) * 64;

  f32x4 acc[4][4];
#pragma unroll
  for (int a = 0; a < 4; ++a)
#pragma unroll
    for (int b = 0; b < 4; ++b)
#pragma unroll
      for (int z = 0; z < 4; ++z) acc[a][b][z] = 0.f;

  for (int k0 = 0; k0 < K; k0 += 32) {
#pragma unroll
    for (int p = 0; p < 2; ++p) {
      int c = p * 256 + wid * 64 + lane;   // lane-linear within wave
      int row = c >> 2, off = c & 3;
      gl_lds16(A  + (size_t)(m0 + row) * K + k0 + off * 8, &As[c * 8]);
      gl_lds16(Bm + (size_t)(n0 + row) * K + k0 + off * 8, &Bs[c * 8]);
    }
    __syncthreads();
    bf16x8 af[4], bfr[4];
#pragma unroll
    for (int mb = 0; mb < 4; ++mb)
      af[mb] = *(const bf16x8*)&As[(wm + mb * 16 + l15) * 32 + quad * 8];
#pragma unroll
    for (int nb = 0; nb < 4; ++nb)
      bfr[nb] = *(const bf16x8*)&Bs[(wn + nb * 16 + l15) * 32 + quad * 8];
#pragma unroll
    for (int mb = 0; mb < 4; ++mb)
#pragma unroll
      for (int nb = 0; nb < 4; ++nb)
        acc[mb][nb] = __builtin_amdgcn_mfma_f32_16x16x32_bf16(af[mb], bfr[nb], acc[mb][nb], 0, 0, 0);
    __syncthreads();
  }

  const float QSCALE = 0.125f * LOG2E;
#pragma unroll
  for (int mb = 0; mb < 4; ++mb) {
    int e0 = m0 + wm + mb * 16 + quad * 4;   // out-dim base for r=0..3
    if (MODE == 0) {
      int s   = e0 >> 9;          // wave-uniform: 0=q,1=k,2=v
      int hh  = (e0 >> 6) & 7;
      int dh0 = e0 & 63;
      unsigned short* dst = (s == 0) ? qo : ((s == 1) ? ko : vo);
      float sc = (s == 0) ? QSCALE : 1.0f;
#pragma unroll
      for (int nb = 0; nb < 4; ++nb) {
        int token = n0 + wn + nb * 16 + l15;
        int bb = token >> 11, ll = token & 2047;
        ushort4 o;
        o.x = f2bf(acc[mb][nb][0] * sc);
        o.y = f2bf(acc[mb][nb][1] * sc);
        o.z = f2bf(acc[mb][nb][2] * sc);
        o.w = f2bf(acc[mb][nb][3] * sc);
        *(ushort4*)&dst[(((size_t)bb * NH + hh) * NL + ll) * DH + dh0] = o;
      }
    } else {
      float4 bv = *(const float4*)&bias[e0];
#pragma unroll
      for (int nb = 0; nb < 4; ++nb) {
        int token = n0 + wn + nb * 16 + l15;
        float4 o;
        o.x = acc[mb][nb][0] + bv.x;
        o.y = acc[mb][nb][1] + bv.y;
        o.z = acc[mb][nb][2] + bv.z;
        o.w = acc[mb][nb][3] + bv.w;
        *(float4*)&out[(size_t)token * ND + e0] = o;
      }
    }
  }
}

// ---------------------------------------------------------------------------
// V transpose: [b,h,l,dh] -> [b,h,dh,l], LDS-tiled, coalesced both sides.
// ---------------------------------------------------------------------------
__global__ __launch_bounds__(256) void transpose_v(const unsigned short* __restrict__ v,
                                                   unsigned short* __restrict__ vT) {
  __shared__ unsigned short T[64][74];
  const int l0 = blockIdx.x * 64;
  const int bh = blockIdx.y;
  const unsigned short* src = v + ((size_t)bh * NL + l0) * DH;
  unsigned short* dst = vT + (size_t)bh * DH * NL;
#pragma unroll
  for (int p = 0; p < 2; ++p) {
    int c = p * 256 + threadIdx.x;
    int row = c >> 3, seg = c & 7;
    *(uint4*)&T[row][seg * 8] = *(const uint4*)(src + row * DH + seg * 8);
  }
  __syncthreads();
#pragma unroll
  for (int p = 0; p < 2; ++p) {
    int c = p * 256 + threadIdx.x;
    int drow = c >> 3, lseg = c & 7;
    unsigned short u[8];
#pragma unroll
    for (int z = 0; z < 8; ++z) u[z] = T[lseg * 8 + z][drow];
    *(uint4*)(dst + (size_t)drow * NL + l0 + lseg * 8) = *(uint4*)u;
  }
}

// ---------------------------------------------------------------------------
// Flash attention, S^T orientation, fixed-shift softmax, split-j=2 partials.
// NO __syncthreads: K/V/position fragments load straight from global; P makes
// a wave-private LDS round-trip (b64 writes / b128 reads).
// Block = 256 thr (4 waves), 128 q-rows/block (32/wave, ib=2 n-blocks).
// accS = mfma(K_frag, Q_frag) => C col = i (lane), row = j (quad*4+reg).
// q pre-scaled by 0.125*log2e => S already in log2 domain.
// ---------------------------------------------------------------------------
__global__ __launch_bounds__(256, 2) void flash_kernel(
    const unsigned short* __restrict__ qb, const unsigned short* __restrict__ kb,
    const unsigned short* __restrict__ vTb, const float* __restrict__ pospad,
    const float* __restrict__ log_sigma, const float* __restrict__ gbias_p,
    const int* __restrict__ ns_p, float* __restrict__ Pbuf, float* __restrict__ rsbuf)
{
  const int it = blockIdx.x >> 1;
  const int js = blockIdx.x & 1;
  const int h  = blockIdx.y;
  const int b  = blockIdx.z;
  const int i0 = it * 128;
  const int jbase = js * (NL / 2);
  const int Ls = ns_p[0];
  const float gb  = gbias_p[0];
  const float sig = __expf(log_sigma[h]);
  const float CI  = LOG2E * 0.5f / (sig * sig);
  const float LGB = LOG2E * gb;
  const float C8N = -8.0f * LOG2E;

  const int tid  = threadIdx.x;
  const int wid  = tid >> 6;      // 0..3
  const int lane = tid & 63;
  const int quad = lane >> 4;
  const int l15  = lane & 15;

  __shared__ __align__(16) unsigned short Pls[4][2][16][72];  // [wave][ib][i][j]

  const size_t bh = (size_t)b * NH + h;
  const unsigned short* qbase  = qb  + (bh * NL + i0 + wid * 32) * DH;
  const unsigned short* kbase  = kb  + bh * NL * DH;
  const unsigned short* vtbase = vTb + bh * DH * NL;
  const float* posb = pospad + (size_t)b * NL * 2;

  // Q B-frags (lane = i) + i-side scalars
  bf16x8 qf[2][2];
  float pix[2], piy[2], ispf[2];
#pragma unroll
  for (int ib = 0; ib < 2; ++ib) {
#pragma unroll
    for (int kc = 0; kc < 2; ++kc)
      qf[ib][kc] = *(const bf16x8*)(qbase + (size_t)(ib * 16 + l15) * DH + kc * 32 + quad * 8);
    int ig = i0 + wid * 32 + ib * 16 + l15;
    float2 p2 = *(const float2*)(posb + (size_t)ig * 2);
    pix[ib] = p2.x; piy[ib] = p2.y;
    ispf[ib] = (ig < Ls) ? 1.f : 0.f;
  }

  f32x4 accO[4][2];   // [dhb][ib], O^T: row=dh(quad*4+r), col=i(l15)
  float rsum[2];
#pragma unroll
  for (int d = 0; d < 4; ++d)
#pragma unroll
    for (int ib = 0; ib < 2; ++ib)
#pragma unroll
      for (int z = 0; z < 4; ++z) accO[d][ib][z] = 0.f;
  rsum[0] = 0.f; rsum[1] = 0.f;

  for (int jt = 0; jt < 16; ++jt) {
    const int j0 = jbase + jt * 64;

    // ---- K A-frags from global (lane = j-row) ----
    bf16x8 kf[4][2];
#pragma unroll
    for (int jb = 0; jb < 4; ++jb)
#pragma unroll
      for (int kc = 0; kc < 2; ++kc)
        kf[jb][kc] = *(const bf16x8*)(kbase + (size_t)(j0 + jb * 16 + l15) * DH + kc * 32 + quad * 8);

    // ---- S^T = K Q^T ----
    f32x4 accS[4][2];
#pragma unroll
    for (int jb = 0; jb < 4; ++jb)
#pragma unroll
      for (int ib = 0; ib < 2; ++ib) {
#pragma unroll
        for (int z = 0; z < 4; ++z) accS[jb][ib][z] = 0.f;
        accS[jb][ib] = __builtin_amdgcn_mfma_f32_16x16x32_bf16(kf[jb][0], qf[ib][0], accS[jb][ib], 0, 0, 0);
        accS[jb][ib] = __builtin_amdgcn_mfma_f32_16x16x32_bf16(kf[jb][1], qf[ib][1], accS[jb][ib], 0, 0, 0);
      }

    // ---- bias + exp2 + P -> LDS (b64 vector writes) ----
#pragma unroll
    for (int jb = 0; jb < 4; ++jb) {
      int jrow = j0 + jb * 16 + quad * 4;
      float4 pA = *(const float4*)(posb + (size_t)jrow * 2);       // px0,py0,px1,py1
      float4 pB = *(const float4*)(posb + (size_t)jrow * 2 + 4);   // px2,py2,px3,py3
      float px[4] = {pA.x, pA.z, pB.x, pB.z};
      float py[4] = {pA.y, pA.w, pB.y, pB.w};
      float jok[4];
#pragma unroll
      for (int r = 0; r < 4; ++r) jok[r] = (jrow + r < Ls) ? 1.f : 0.f;
#pragma unroll
      for (int ib = 0; ib < 2; ++ib) {
        float p[4];
#pragma unroll
        for (int r = 0; r < 4; ++r) {
          float dx = pix[ib] - px[r];
          float dy = piy[ib] - py[r];
          float d2 = __builtin_fmaf(dx, dx, dy * dy);
          float u  = __builtin_fmaf(CI, d2, LGB);
          float m  = jok[r] * ispf[ib];
          float t  = __builtin_fmaf(-m, u, accS[jb][ib][r] + C8N);
          p[r] = fexp2(t);
        }
        rsum[ib] += (p[0] + p[1]) + (p[2] + p[3]);
        uint2 w;
        w.x = (uint32_t)f2bf(p[0]) | ((uint32_t)f2bf(p[1]) << 16);
        w.y = (uint32_t)f2bf(p[2]) | ((uint32_t)f2bf(p[3]) << 16);
        *(uint2*)&Pls[wid][ib][l15][jb * 16 + quad * 4] = w;
      }
    }

    // ---- O^T += V^T P^T (P B-frags: b128 reads, wave-private => no barrier) ----
    bf16x8 pbf[2][2];
#pragma unroll
    for (int ib = 0; ib < 2; ++ib)
#pragma unroll
      for (int pp = 0; pp < 2; ++pp)
        pbf[ib][pp] = *(const bf16x8*)&Pls[wid][ib][l15][pp * 32 + quad * 8];
#pragma unroll
    for (int dhb = 0; dhb < 4; ++dhb)
#pragma unroll
      for (int pp = 0; pp < 2; ++pp) {
        bf16x8 vf = *(const bf16x8*)(vtbase + (size_t)(dhb * 16 + l15) * NL + j0 + pp * 32 + quad * 8);
#pragma unroll
        for (int ib = 0; ib < 2; ++ib)
          accO[dhb][ib] = __builtin_amdgcn_mfma_f32_16x16x32_bf16(vf, pbf[ib][pp], accO[dhb][ib], 0, 0, 0);
      }
  }

  // ---- epilogue: unnormalized partials ----
#pragma unroll
  for (int ib = 0; ib < 2; ++ib) {
    float v = rsum[ib];
    v += __shfl_xor(v, 16);
    v += __shfl_xor(v, 32);
    int ig = i0 + wid * 32 + ib * 16 + l15;
    if (quad == 0)
      rsbuf[(size_t)js * RG_TOT + bh * NL + ig] = v;
#pragma unroll
    for (int dhb = 0; dhb < 4; ++dhb) {
      float4 o;
      o.x = accO[dhb][ib][0]; o.y = accO[dhb][ib][1];
      o.z = accO[dhb][ib][2]; o.w = accO[dhb][ib][3];
      *(float4*)&Pbuf[((size_t)js * RG_TOT + bh * NL + ig) * DH + dhb * 16 + quad * 4] = o;
    }
  }
}

// ---------------------------------------------------------------------------
// Combine split-j partials -> bf16 attn [b, l, h*64+dh]
// ---------------------------------------------------------------------------
__global__ __launch_bounds__(256) void combine_kernel(const float* __restrict__ Pbuf,
                                                      const float* __restrict__ rsbuf,
                                                      unsigned short* __restrict__ attnb) {
  int idx = blockIdx.x * 256 + threadIdx.x;       // over RG_TOT*16 float4 chunks
  int rg = idx >> 4, c4 = idx & 15;
  const float4* p4 = (const float4*)Pbuf;
  float4 p0 = p4[(size_t)rg * 16 + c4];
  float4 p1 = p4[(size_t)RG_TOT * 16 + (size_t)rg * 16 + c4];
  float rs = 1.0f / (rsbuf[rg] + rsbuf[RG_TOT + rg]);
  int bhm = rg >> 11;           // b*8+h
  int l   = rg & 2047;
  int bb  = bhm >> 3, hh = bhm & 7;
  ushort4 o;
  o.x = f2bf((p0.x + p1.x) * rs);
  o.y = f2bf((p0.y + p1.y) * rs);
  o.z = f2bf((p0.z + p1.z) * rs);
  o.w = f2bf((p0.w + p1.w) * rs);
  *(ushort4*)&attnb[(((size_t)bb * NL + l) * ND) + hh * DH + c4 * 4] = o;
}

// ---------------------------------------------------------------------------
extern "C" void kernel_launch(void* const* d_in, const int* in_sizes, int n_in,
                              void* d_out, int out_size, void* d_ws, size_t ws_size,
                              hipStream_t stream) {
  const float* x         = (const float*)d_in[0];
  const float* positions = (const float*)d_in[1];
  const float* w_qkv     = (const float*)d_in[2];
  const float* w_out     = (const float*)d_in[3];
  const float* b_out     = (const float*)d_in[4];
  const float* log_sigma = (const float*)d_in[5];
  const float* gbias     = (const float*)d_in[6];
  const int*   ns        = (const int*)d_in[7];

  // workspace layout
  unsigned short* ws = (unsigned short*)d_ws;
  unsigned short* xb  = ws;                    // 2,097,152 shorts (reused as attn bf16)
  unsigned short* wqb = xb  + 2097152;         //   786,432
  unsigned short* wob = wqb + 786432;          //   262,144
  unsigned short* qbf = wob + 262144;          // 2,097,152
  unsigned short* kbf = qbf + 2097152;         // 2,097,152
  unsigned short* vbf = kbf + 2097152;         // 2,097,152
  unsigned short* vTf = vbf + 2097152;         // 2,097,152
  float* Pbuf   = (float*)(vTf + 2097152);     // 2 * 32768 * 64 f32 = 16.8 MB
  float* rsbuf  = Pbuf + (size_t)2 * RG_TOT * DH;
  float* pospad = rsbuf + 2 * RG_TOT;          // NB * 2048 * 2 f32

  // 1) f32 -> bf16 + padded positions
  cvt_f32_bf16<<<(TOTC + NB * 1024 + 255) / 256, 256, 0, stream>>>(
      x, w_qkv, w_out, positions, ns, xb, wqb, wob, pospad);

  // 2) QKV projection (swapped: A=w_qkv rows, B=token rows) -> q(scaled), k, v
  dim3 g1((3 * NH * DH) / 128, NB * NL / 128);
  gemm_bf16<0><<<g1, 256, 0, stream>>>(wqb, xb, nullptr, qbf, kbf, vbf, nullptr, ND);

  // 3) V transpose -> [b,h,dh,l]
  dim3 gt(NL / 64, NB * NH);
  transpose_v<<<gt, 256, 0, stream>>>(vbf, vTf);

  // 4) flash attention partials (split-j=2), barrier-free
  dim3 g2((NL / 128) * 2, NH, NB);
  flash_kernel<<<g2, 256, 0, stream>>>(qbf, kbf, vTf, pospad, log_sigma, gbias, ns,
                                       Pbuf, rsbuf);

  // 5) combine -> bf16 attn (into xb)
  combine_kernel<<<RG_TOT * 16 / 256, 256, 0, stream>>>(Pbuf, rsbuf, xb);

  // 6) output projection (swapped: A=w_out rows, B=attn tokens) + bias -> f32
  dim3 g3(ND / 128, NB * NL / 128);
  gemm_bf16<1><<<g3, 256, 0, stream>>>(wob, xb, b_out, nullptr, nullptr, nullptr,
                                       (float*)d_out, NH * DH);
}

// Round 5
// 190.512 us; speedup vs baseline: 1.0465x; 1.0465x over previous
//
#include <hip/hip_runtime.h>
#include <stdint.h>
#include <stddef.h>

// Problem constants (fixed by setup_inputs)
#define NB   2      // batch
#define NL   2048   // seq len
#define ND   512    // model dim
#define NH   8      // heads
#define DH   64     // dim head
#define LOG2E 1.44269504f
#define RG_TOT 32768  // NB*NH*NL rows of partials

typedef __attribute__((ext_vector_type(8))) short bf16x8;
typedef __attribute__((ext_vector_type(4))) float f32x4;

__device__ __forceinline__ unsigned short f2bf(float f) {
  union { float f; unsigned int u; } c; c.f = f;
  unsigned int u = c.u;
  unsigned int r = u + 0x7fffu + ((u >> 16) & 1u);
  return (unsigned short)(r >> 16);
}

__device__ __forceinline__ float fexp2(float x) {
#if __has_builtin(__builtin_amdgcn_exp2f)
  return __builtin_amdgcn_exp2f(x);
#else
  return exp2f(x);
#endif
}

// async global->LDS 16B copy; lanes of a wave must target base + lane*16
__device__ __forceinline__ void gl_lds16(const unsigned short* g, unsigned short* l) {
#if __has_builtin(__builtin_amdgcn_global_load_lds)
  __builtin_amdgcn_global_load_lds(
      (const __attribute__((address_space(1))) unsigned int*)g,
      (__attribute__((address_space(3))) unsigned int*)l, 16, 0, 0);
#else
  *(uint4*)l = *(const uint4*)g;
#endif
}

// ---------------------------------------------------------------------------
// f32 -> bf16 conversion for x, w_qkv, w_out + zero-padded positions buffer
// ---------------------------------------------------------------------------
#define XC  524288   // 4096*512/4
#define WQC 196608   // 1536*512/4
#define WOC 65536    // 512*512/4
#define TOTC (XC + WQC + WOC)
__global__ void cvt_f32_bf16(const float* __restrict__ x, const float* __restrict__ wq,
                             const float* __restrict__ wo, const float* __restrict__ positions,
                             const int* __restrict__ ns_p,
                             unsigned short* __restrict__ xb, unsigned short* __restrict__ wqb,
                             unsigned short* __restrict__ wob, float* __restrict__ pospad) {
  int idx = blockIdx.x * 256 + threadIdx.x;
  if (idx < TOTC) {
    const float* src; unsigned short* dst; int off;
    if (idx < XC)            { src = x;  dst = xb;  off = idx; }
    else if (idx < XC + WQC) { src = wq; dst = wqb; off = idx - XC; }
    else                     { src = wo; dst = wob; off = idx - XC - WQC; }
    float4 f = ((const float4*)src)[off];
    ushort4 o;
    o.x = f2bf(f.x); o.y = f2bf(f.y); o.z = f2bf(f.z); o.w = f2bf(f.w);
    ((ushort4*)dst)[off] = o;
  } else {
    int i2 = idx - TOTC;
    if (i2 < NB * 1024) {
      int b = i2 >> 10;
      int jj = (i2 & 1023) * 2;
      int Ls = ns_p[0];
      float4 o = make_float4(0.f, 0.f, 0.f, 0.f);
      if (jj < Ls) { o.x = positions[((size_t)b * Ls + jj) * 2];
                     o.y = positions[((size_t)b * Ls + jj) * 2 + 1]; }
      if (jj + 1 < Ls) { o.z = positions[((size_t)b * Ls + jj + 1) * 2];
                         o.w = positions[((size_t)b * Ls + jj + 1) * 2 + 1]; }
      *(float4*)&pospad[((size_t)b * NL + jj) * 2] = o;
    }
  }
}

// ---------------------------------------------------------------------------
// bf16 128x128-tile MFMA GEMM, SWAPPED orientation: A = weights (M=out-dim),
// B = tokens (N=4096). C row (quad/reg) = out-dim -> vectorized epilogues.
// MODE 0: A=w_qkv[1536x512] -> q(pre-scaled)/k/v bf16 [b,h,l,dh] (ushort4 st).
// MODE 1: A=w_out[512x512], B=attn -> f32 out[token][512] + bias (float4 st).
// ---------------------------------------------------------------------------
template<int MODE>
__global__ __launch_bounds__(256, 2) void gemm_bf16(
    const unsigned short* __restrict__ A, const unsigned short* __restrict__ Bm,
    const float* __restrict__ bias,
    unsigned short* __restrict__ qo, unsigned short* __restrict__ ko,
    unsigned short* __restrict__ vo, float* __restrict__ out, int K)
{
  __shared__ __align__(16) unsigned short As[128 * 32];
  __shared__ __align__(16) unsigned short Bs[128 * 32];
  const int tid = threadIdx.x, wid = tid >> 6, lane = tid & 63;
  const int quad = lane >> 4, l15 = lane & 15;
  const int m0 = blockIdx.x * 128, n0 = blockIdx.y * 128;
  const int wm = (wid >> 1) * 64, wn = (wid & 1) * 64;

  f32x4 acc[4][4];
#pragma unroll
  for (int a = 0; a < 4; ++a)
#pragma unroll
    for (int b = 0; b < 4; ++b)
#pragma unroll
      for (int z = 0; z < 4; ++z) acc[a][b][z] = 0.f;

  for (int k0 = 0; k0 < K; k0 += 32) {
#pragma unroll
    for (int p = 0; p < 2; ++p) {
      int c = p * 256 + wid * 64 + lane;   // lane-linear within wave
      int row = c >> 2, off = c & 3;
      gl_lds16(A  + (size_t)(m0 + row) * K + k0 + off * 8, &As[c * 8]);
      gl_lds16(Bm + (size_t)(n0 + row) * K + k0 + off * 8, &Bs[c * 8]);
    }
    __syncthreads();
    bf16x8 af[4], bfr[4];
#pragma unroll
    for (int mb = 0; mb < 4; ++mb)
      af[mb] = *(const bf16x8*)&As[(wm + mb * 16 + l15) * 32 + quad * 8];
#pragma unroll
    for (int nb = 0; nb < 4; ++nb)
      bfr[nb] = *(const bf16x8*)&Bs[(wn + nb * 16 + l15) * 32 + quad * 8];
#pragma unroll
    for (int mb = 0; mb < 4; ++mb)
#pragma unroll
      for (int nb = 0; nb < 4; ++nb)
        acc[mb][nb] = __builtin_amdgcn_mfma_f32_16x16x32_bf16(af[mb], bfr[nb], acc[mb][nb], 0, 0, 0);
    __syncthreads();
  }

  const float QSCALE = 0.125f * LOG2E;
#pragma unroll
  for (int mb = 0; mb < 4; ++mb) {
    int e0 = m0 + wm + mb * 16 + quad * 4;   // out-dim base for r=0..3
    if (MODE == 0) {
      int s   = e0 >> 9;          // wave-uniform: 0=q,1=k,2=v
      int hh  = (e0 >> 6) & 7;
      int dh0 = e0 & 63;
      unsigned short* dst = (s == 0) ? qo : ((s == 1) ? ko : vo);
      float sc = (s == 0) ? QSCALE : 1.0f;
#pragma unroll
      for (int nb = 0; nb < 4; ++nb) {
        int token = n0 + wn + nb * 16 + l15;
        int bb = token >> 11, ll = token & 2047;
        ushort4 o;
        o.x = f2bf(acc[mb][nb][0] * sc);
        o.y = f2bf(acc[mb][nb][1] * sc);
        o.z = f2bf(acc[mb][nb][2] * sc);
        o.w = f2bf(acc[mb][nb][3] * sc);
        *(ushort4*)&dst[(((size_t)bb * NH + hh) * NL + ll) * DH + dh0] = o;
      }
    } else {
      float4 bv = *(const float4*)&bias[e0];
#pragma unroll
      for (int nb = 0; nb < 4; ++nb) {
        int token = n0 + wn + nb * 16 + l15;
        float4 o;
        o.x = acc[mb][nb][0] + bv.x;
        o.y = acc[mb][nb][1] + bv.y;
        o.z = acc[mb][nb][2] + bv.z;
        o.w = acc[mb][nb][3] + bv.w;
        *(float4*)&out[(size_t)token * ND + e0] = o;
      }
    }
  }
}

// ---------------------------------------------------------------------------
// V transpose: [b,h,l,dh] -> [b,h,dh,l], LDS-tiled, coalesced both sides.
// ---------------------------------------------------------------------------
__global__ __launch_bounds__(256) void transpose_v(const unsigned short* __restrict__ v,
                                                   unsigned short* __restrict__ vT) {
  __shared__ unsigned short T[64][74];
  const int l0 = blockIdx.x * 64;
  const int bh = blockIdx.y;
  const unsigned short* src = v + ((size_t)bh * NL + l0) * DH;
  unsigned short* dst = vT + (size_t)bh * DH * NL;
#pragma unroll
  for (int p = 0; p < 2; ++p) {
    int c = p * 256 + threadIdx.x;
    int row = c >> 3, seg = c & 7;
    *(uint4*)&T[row][seg * 8] = *(const uint4*)(src + row * DH + seg * 8);
  }
  __syncthreads();
#pragma unroll
  for (int p = 0; p < 2; ++p) {
    int c = p * 256 + threadIdx.x;
    int drow = c >> 3, lseg = c & 7;
    unsigned short u[8];
#pragma unroll
    for (int z = 0; z < 8; ++z) u[z] = T[lseg * 8 + z][drow];
    *(uint4*)(dst + (size_t)drow * NL + l0 + lseg * 8) = *(uint4*)u;
  }
}

// ---------------------------------------------------------------------------
// Flash attention: S^T orientation + LDS-staged K/V^T tiles (R3 staging,
// R4 P-path). Fixed-shift softmax, split-j=2 partials.
// Block = 256 thr (4 waves), 128 q-rows/block (32/wave via l15, ib=2).
// accS = mfma(K_frag, Q_frag) => C col = i (lane), row = j (quad*4+reg):
//   P store = b64 vector writes, P re-load = b128 reads (wave-private).
// q pre-scaled by 0.125*log2e => S already in log2 domain.
// ---------------------------------------------------------------------------
__global__ __launch_bounds__(256, 2) void flash_kernel(
    const unsigned short* __restrict__ qb, const unsigned short* __restrict__ kb,
    const unsigned short* __restrict__ vTb, const float* __restrict__ pospad,
    const float* __restrict__ log_sigma, const float* __restrict__ gbias_p,
    const int* __restrict__ ns_p, float* __restrict__ Pbuf, float* __restrict__ rsbuf)
{
  const int it = blockIdx.x >> 1;
  const int js = blockIdx.x & 1;
  const int h  = blockIdx.y;
  const int b  = blockIdx.z;
  const int i0 = it * 128;
  const int jbase = js * (NL / 2);
  const int Ls = ns_p[0];
  const float gb  = gbias_p[0];
  const float sig = __expf(log_sigma[h]);
  const float CI  = LOG2E * 0.5f / (sig * sig);
  const float LGB = LOG2E * gb;
  const float CB  = -8.0f * LOG2E + LGB;   // fixed shift + global-bias floor

  const int tid  = threadIdx.x;
  const int wid  = tid >> 6;      // 0..3
  const int lane = tid & 63;
  const int quad = lane >> 4;
  const int l15  = lane & 15;

  __shared__ __align__(16) unsigned short Ks[64][72];           // [j][dh]
  __shared__ __align__(16) unsigned short Vt[64][72];           // [dh][j]
  __shared__ __align__(16) unsigned short Pls[4][2][16][72];    // [wave][ib][i][j]

  const size_t bh = (size_t)b * NH + h;
  const unsigned short* qbase  = qb  + (bh * NL + i0 + wid * 32) * DH;
  const unsigned short* kbase  = kb  + bh * NL * DH;
  const unsigned short* vtbase = vTb + bh * DH * NL;
  const float* posb = pospad + (size_t)b * NL * 2;

  // Q B-frags (lane = i) + i-side scalars
  bf16x8 qf[2][2];
  float pix[2], piy[2], ispf[2];
#pragma unroll
  for (int ib = 0; ib < 2; ++ib) {
#pragma unroll
    for (int kc = 0; kc < 2; ++kc)
      qf[ib][kc] = *(const bf16x8*)(qbase + (size_t)(ib * 16 + l15) * DH + kc * 32 + quad * 8);
    int ig = i0 + wid * 32 + ib * 16 + l15;
    float2 p2 = *(const float2*)(posb + (size_t)ig * 2);
    pix[ib] = p2.x; piy[ib] = p2.y;
    ispf[ib] = (ig < Ls) ? 1.f : 0.f;
  }

  f32x4 accO[4][2];   // [dhb][ib], O^T: row=dh(quad*4+r), col=i(l15)
  float rsum[2];
#pragma unroll
  for (int d = 0; d < 4; ++d)
#pragma unroll
    for (int ib = 0; ib < 2; ++ib)
#pragma unroll
      for (int z = 0; z < 4; ++z) accO[d][ib][z] = 0.f;
  rsum[0] = 0.f; rsum[1] = 0.f;

  // ---- register prefetch of tile 0 (coalesced) ----
  uint4 kr[2], vr[2];
  {
#pragma unroll
    for (int p = 0; p < 2; ++p) {
      int c = p * 256 + tid;          // 512 chunks: 64 rows x 8 segs of 16B
      int row = c >> 3, off = c & 7;
      kr[p] = *(const uint4*)(kbase  + (size_t)(jbase + row) * DH + off * 8);
      vr[p] = *(const uint4*)(vtbase + (size_t)row * NL + jbase + off * 8);
    }
  }

  for (int jt = 0; jt < 16; ++jt) {
    const int j0 = jbase + jt * 64;
    __syncthreads();   // prior iteration's LDS reads complete

    // regs -> LDS (padded stride 72: balanced bank spread)
#pragma unroll
    for (int p = 0; p < 2; ++p) {
      int c = p * 256 + tid;
      int row = c >> 3, off = c & 7;
      *(uint4*)&Ks[row][off * 8] = kr[p];
      *(uint4*)&Vt[row][off * 8] = vr[p];
    }
    __syncthreads();

    // prefetch next tile
    if (jt + 1 < 16) {
      const int jn = jbase + (jt + 1) * 64;
#pragma unroll
      for (int p = 0; p < 2; ++p) {
        int c = p * 256 + tid;
        int row = c >> 3, off = c & 7;
        kr[p] = *(const uint4*)(kbase  + (size_t)(jn + row) * DH + off * 8);
        vr[p] = *(const uint4*)(vtbase + (size_t)row * NL + jn + off * 8);
      }
    }

    // ---- K A-frags from LDS (b128 reads) ----
    bf16x8 kf[4][2];
#pragma unroll
    for (int jb = 0; jb < 4; ++jb)
#pragma unroll
      for (int kc = 0; kc < 2; ++kc)
        kf[jb][kc] = *(const bf16x8*)&Ks[jb * 16 + l15][kc * 32 + quad * 8];

    // ---- S^T = K Q^T ----
    f32x4 accS[4][2];
#pragma unroll
    for (int jb = 0; jb < 4; ++jb)
#pragma unroll
      for (int ib = 0; ib < 2; ++ib) {
#pragma unroll
        for (int z = 0; z < 4; ++z) accS[jb][ib][z] = 0.f;
        accS[jb][ib] = __builtin_amdgcn_mfma_f32_16x16x32_bf16(kf[jb][0], qf[ib][0], accS[jb][ib], 0, 0, 0);
        accS[jb][ib] = __builtin_amdgcn_mfma_f32_16x16x32_bf16(kf[jb][1], qf[ib][1], accS[jb][ib], 0, 0, 0);
      }

    // ---- bias + exp2 + P -> LDS (b64 vector writes) ----
#pragma unroll
    for (int jb = 0; jb < 4; ++jb) {
      int jrow = j0 + jb * 16 + quad * 4;
      float4 pA = *(const float4*)(posb + (size_t)jrow * 2);       // px0,py0,px1,py1
      float4 pB = *(const float4*)(posb + (size_t)jrow * 2 + 4);   // px2,py2,px3,py3
      float px[4] = {pA.x, pA.z, pB.x, pB.z};
      float py[4] = {pA.y, pA.w, pB.y, pB.w};
      float jok[4];
#pragma unroll
      for (int r = 0; r < 4; ++r) jok[r] = (jrow + r < Ls) ? 1.f : 0.f;
#pragma unroll
      for (int ib = 0; ib < 2; ++ib) {
        float p[4];
#pragma unroll
        for (int r = 0; r < 4; ++r) {
          float dx = pix[ib] - px[r];
          float dy = piy[ib] - py[r];
          float d2 = __builtin_fmaf(dx, dx, dy * dy);
          float u  = __builtin_fmaf(CI, d2, LGB);     // spatial-vs-global delta
          float m  = jok[r] * ispf[ib];
          float t  = __builtin_fmaf(-m, u, accS[jb][ib][r] + CB);
          p[r] = fexp2(t);
        }
        rsum[ib] += (p[0] + p[1]) + (p[2] + p[3]);
        uint2 w;
        w.x = (uint32_t)f2bf(p[0]) | ((uint32_t)f2bf(p[1]) << 16);
        w.y = (uint32_t)f2bf(p[2]) | ((uint32_t)f2bf(p[3]) << 16);
        *(uint2*)&Pls[wid][ib][l15][jb * 16 + quad * 4] = w;
      }
    }

    // ---- O^T += V^T P^T (wave-private Pls: no barrier; V A-frags from LDS) ----
    bf16x8 pbf[2][2];
#pragma unroll
    for (int ib = 0; ib < 2; ++ib)
#pragma unroll
      for (int pp = 0; pp < 2; ++pp)
        pbf[ib][pp] = *(const bf16x8*)&Pls[wid][ib][l15][pp * 32 + quad * 8];
#pragma unroll
    for (int dhb = 0; dhb < 4; ++dhb)
#pragma unroll
      for (int pp = 0; pp < 2; ++pp) {
        bf16x8 vf = *(const bf16x8*)&Vt[dhb * 16 + l15][pp * 32 + quad * 8];
#pragma unroll
        for (int ib = 0; ib < 2; ++ib)
          accO[dhb][ib] = __builtin_amdgcn_mfma_f32_16x16x32_bf16(vf, pbf[ib][pp], accO[dhb][ib], 0, 0, 0);
      }
  }

  // ---- epilogue: unnormalized partials ----
#pragma unroll
  for (int ib = 0; ib < 2; ++ib) {
    float v = rsum[ib];
    v += __shfl_xor(v, 16);
    v += __shfl_xor(v, 32);
    int ig = i0 + wid * 32 + ib * 16 + l15;
    if (quad == 0)
      rsbuf[(size_t)js * RG_TOT + bh * NL + ig] = v;
#pragma unroll
    for (int dhb = 0; dhb < 4; ++dhb) {
      float4 o;
      o.x = accO[dhb][ib][0]; o.y = accO[dhb][ib][1];
      o.z = accO[dhb][ib][2]; o.w = accO[dhb][ib][3];
      *(float4*)&Pbuf[((size_t)js * RG_TOT + bh * NL + ig) * DH + dhb * 16 + quad * 4] = o;
    }
  }
}

// ---------------------------------------------------------------------------
// Combine split-j partials -> bf16 attn [b, l, h*64+dh]
// ---------------------------------------------------------------------------
__global__ __launch_bounds__(256) void combine_kernel(const float* __restrict__ Pbuf,
                                                      const float* __restrict__ rsbuf,
                                                      unsigned short* __restrict__ attnb) {
  int idx = blockIdx.x * 256 + threadIdx.x;       // over RG_TOT*16 float4 chunks
  int rg = idx >> 4, c4 = idx & 15;
  const float4* p4 = (const float4*)Pbuf;
  float4 p0 = p4[(size_t)rg * 16 + c4];
  float4 p1 = p4[(size_t)RG_TOT * 16 + (size_t)rg * 16 + c4];
  float rs = 1.0f / (rsbuf[rg] + rsbuf[RG_TOT + rg]);
  int bhm = rg >> 11;           // b*8+h
  int l   = rg & 2047;
  int bb  = bhm >> 3, hh = bhm & 7;
  ushort4 o;
  o.x = f2bf((p0.x + p1.x) * rs);
  o.y = f2bf((p0.y + p1.y) * rs);
  o.z = f2bf((p0.z + p1.z) * rs);
  o.w = f2bf((p0.w + p1.w) * rs);
  *(ushort4*)&attnb[(((size_t)bb * NL + l) * ND) + hh * DH + c4 * 4] = o;
}

// ---------------------------------------------------------------------------
extern "C" void kernel_launch(void* const* d_in, const int* in_sizes, int n_in,
                              void* d_out, int out_size, void* d_ws, size_t ws_size,
                              hipStream_t stream) {
  const float* x         = (const float*)d_in[0];
  const float* positions = (const float*)d_in[1];
  const float* w_qkv     = (const float*)d_in[2];
  const float* w_out     = (const float*)d_in[3];
  const float* b_out     = (const float*)d_in[4];
  const float* log_sigma = (const float*)d_in[5];
  const float* gbias     = (const float*)d_in[6];
  const int*   ns        = (const int*)d_in[7];

  // workspace layout
  unsigned short* ws = (unsigned short*)d_ws;
  unsigned short* xb  = ws;                    // 2,097,152 shorts (reused as attn bf16)
  unsigned short* wqb = xb  + 2097152;         //   786,432
  unsigned short* wob = wqb + 786432;          //   262,144
  unsigned short* qbf = wob + 262144;          // 2,097,152
  unsigned short* kbf = qbf + 2097152;         // 2,097,152
  unsigned short* vbf = kbf + 2097152;         // 2,097,152
  unsigned short* vTf = vbf + 2097152;         // 2,097,152
  float* Pbuf   = (float*)(vTf + 2097152);     // 2 * 32768 * 64 f32 = 16.8 MB
  float* rsbuf  = Pbuf + (size_t)2 * RG_TOT * DH;
  float* pospad = rsbuf + 2 * RG_TOT;          // NB * 2048 * 2 f32

  // 1) f32 -> bf16 + padded positions
  cvt_f32_bf16<<<(TOTC + NB * 1024 + 255) / 256, 256, 0, stream>>>(
      x, w_qkv, w_out, positions, ns, xb, wqb, wob, pospad);

  // 2) QKV projection (swapped: A=w_qkv rows, B=token rows) -> q(scaled), k, v
  dim3 g1((3 * NH * DH) / 128, NB * NL / 128);
  gemm_bf16<0><<<g1, 256, 0, stream>>>(wqb, xb, nullptr, qbf, kbf, vbf, nullptr, ND);

  // 3) V transpose -> [b,h,dh,l]
  dim3 gt(NL / 64, NB * NH);
  transpose_v<<<gt, 256, 0, stream>>>(vbf, vTf);

  // 4) flash attention partials (split-j=2), LDS-staged tiles
  dim3 g2((NL / 128) * 2, NH, NB);
  flash_kernel<<<g2, 256, 0, stream>>>(qbf, kbf, vTf, pospad, log_sigma, gbias, ns,
                                       Pbuf, rsbuf);

  // 5) combine -> bf16 attn (into xb)
  combine_kernel<<<RG_TOT * 16 / 256, 256, 0, stream>>>(Pbuf, rsbuf, xb);

  // 6) output projection (swapped: A=w_out rows, B=attn tokens) + bias -> f32
  dim3 g3(ND / 128, NB * NL / 128);
  gemm_bf16<1><<<g3, 256, 0, stream>>>(wob, xb, b_out, nullptr, nullptr, nullptr,
                                       (float*)d_out, NH * DH);
}